// Round 14
// baseline (147.831 us; speedup 1.0000x reference)
//
#include <hip/hip_runtime.h>

#define B_ 64
#define L_ 1024
#define M_ 256
#define F_ 256

typedef __attribute__((ext_vector_type(8))) short short8;    // 8 bf16 (4 VGPR)
typedef __attribute__((ext_vector_type(16))) float f32x16;   // 32x32 MFMA C/D
typedef unsigned int u32;

struct Frag3 { short8 h, m, l; };

__device__ __forceinline__ u32 asu(float f) { union { float f; u32 u; } c; c.f = f; return c.u; }
__device__ __forceinline__ float asf(u32 u) { union { float f; u32 u; } c; c.u = u; return c.f; }
__device__ __forceinline__ u32 pack2(u32 lo, u32 hi) {
    return __builtin_amdgcn_perm(hi, lo, 0x07060302u);
}
__device__ __forceinline__ float4 ld4(const float* p) {
    return *reinterpret_cast<const float4*>(p);
}

// Async 16B global->LDS DMA; LDS dest wave-uniform, per-lane source carries
// the XOR swizzle (m173 pattern, validated R6/R10).
__device__ __forceinline__ void async_cp16(const float* g, float* l) {
    __builtin_amdgcn_global_load_lds(
        (const __attribute__((address_space(1))) u32*)g,
        (__attribute__((address_space(3))) u32*)l,
        16, 0, 0);
}

// Exact 3-way bf16 truncation split of 8 fp32: x = h + m + l (top 24 mantissa bits).
__device__ __forceinline__ Frag3 split8(float4 a, float4 b) {
    float x[8] = {a.x, a.y, a.z, a.w, b.x, b.y, b.z, b.w};
    u32 xb[8], rb[8], sb[8];
#pragma unroll
    for (int e = 0; e < 8; ++e) {
        xb[e] = asu(x[e]);
        float hf = asf(xb[e] & 0xFFFF0000u);
        float r  = x[e] - hf;                 // exact
        rb[e] = asu(r);
        float mf = asf(rb[e] & 0xFFFF0000u);
        float r2 = r - mf;                    // exact
        sb[e] = asu(r2);
    }
    union { u32 w[4]; short8 s; } H, M, Lo;
#pragma unroll
    for (int d = 0; d < 4; ++d) {
        H.w[d]  = pack2(xb[2 * d], xb[2 * d + 1]);
        M.w[d]  = pack2(rb[2 * d], rb[2 * d + 1]);
        Lo.w[d] = pack2(sb[2 * d], sb[2 * d + 1]);
    }
    Frag3 f; f.h = H.s; f.m = M.s; f.l = Lo.s; return f;
}

#define MFMA6(ACC, A, Bf)                                                        \
    ACC = __builtin_amdgcn_mfma_f32_32x32x16_bf16((A).m, (Bf).m, ACC, 0, 0, 0);  \
    ACC = __builtin_amdgcn_mfma_f32_32x32x16_bf16((A).h, (Bf).l, ACC, 0, 0, 0);  \
    ACC = __builtin_amdgcn_mfma_f32_32x32x16_bf16((A).l, (Bf).h, ACC, 0, 0, 0);  \
    ACC = __builtin_amdgcn_mfma_f32_32x32x16_bf16((A).h, (Bf).m, ACC, 0, 0, 0);  \
    ACC = __builtin_amdgcn_mfma_f32_32x32x16_bf16((A).m, (Bf).h, ACC, 0, 0, 0);  \
    ACC = __builtin_amdgcn_mfma_f32_32x32x16_bf16((A).h, (Bf).h, ACC, 0, 0, 0)

// One block per l, 1024 threads = 16 waves, 1 block/CU (LDS = 160KB exactly).
// Wave (bt=w&1, mtg=w>>1): b-rows bt*32..+31, m-cols mtg*32..+31, acc = 1
// f32x16. K tiled by 32 f, QUAD-buffered LDS staged by global_load_lds:
// tile ft+3 staged at iter ft -> ~3 compute phases of load cover; counted
// per-wave vmcnt (waves 0-7: 3 chunks/tile incl. P, waves 8-15: 2), exact
// end-game immediates via full unroll. Never drains to 0 until ft=7.
// D layout: col(m)=lane&31, row=(reg&3)+8*(reg>>2)+4*(lane>>5)  [m74/m101].
__launch_bounds__(1024)
__global__ void mq_mfma_q4_kernel(const float* __restrict__ patch,
                                  const float* __restrict__ queue,
                                  float* __restrict__ out) {
    const int l    = blockIdx.x;
    const int t    = threadIdx.x;
    const int lane = t & 63;
    const int w    = t >> 6;        // 0..15
    const int bt   = w & 1;
    const int mtg  = w >> 1;        // 0..7
    const int r32  = lane & 31;
    const int kh   = lane >> 5;     // k-half: f-offset kh*8
    const bool w8  = (w < 8);

    __shared__ __align__(16) float Ql[4][256 * 32];  // 4 x 32KB = 128KB
    __shared__ __align__(16) float Pl[4][64 * 32];   // 4 x  8KB =  32KB

    // ---- staging geometry: wave w stages Q chunks 2w,2w+1 (rows w*16..+15);
    //      waves 0-7 also stage P chunk w (rows w*8..+7). Chunk = 8 rows x
    //      128B; source 16B-slot pre-swizzled: chunk (lcol^lrow).
    const int lrow = lane >> 3;     // 0..7: row within an 8-row chunk
    const int lcol = lane & 7;      // 0..7: 16B slot within a 128B row
    const float* qsrcw = queue + ((size_t)l * M_ + w * 16 + lrow) * F_ + (lcol ^ lrow) * 4;
    const float* psrcw = patch + ((size_t)((w & 7) * 8 + lrow) * L_ + l) * F_ + (lcol ^ lrow) * 4;

#define STAGE(FT, BUF)                                                            \
    {                                                                             \
        async_cp16(qsrcw + (FT) * 32, &Ql[BUF][(2 * w) * 256]);                   \
        async_cp16(qsrcw + (size_t)8 * F_ + (FT) * 32, &Ql[BUF][(2 * w + 1) * 256]); \
        if (w8) async_cp16(psrcw + (FT) * 32, &Pl[BUF][w * 256]);                 \
    }

    f32x16 acc = (f32x16)0.f;

    const int s7  = r32 & 7;         // read-side XOR (row&7 == r32&7 everywhere)
    const int ra  = bt * 32 + r32;   // P row for this lane
    const int rbm = mtg * 32 + r32;  // Q row for this lane

#define COMPUTE(FT)                                                               \
    {                                                                             \
        const float* Qb = &Ql[(FT) & 3][0];                                       \
        const float* Pb = &Pl[(FT) & 3][0];                                       \
        _Pragma("unroll")                                                         \
        for (int kk = 0; kk < 2; ++kk) {                                          \
            const int c0 = kk * 4 + kh * 2;                                       \
            const float4 a0 = ld4(&Pb[ra * 32 + ((c0 ^ s7) * 4)]);                \
            const float4 a1 = ld4(&Pb[ra * 32 + (((c0 + 1) ^ s7) * 4)]);          \
            const Frag3 A = split8(a0, a1);                                       \
            const float4 b0 = ld4(&Qb[rbm * 32 + ((c0 ^ s7) * 4)]);               \
            const float4 b1 = ld4(&Qb[rbm * 32 + (((c0 + 1) ^ s7) * 4)]);         \
            const Frag3 Bf = split8(b0, b1);                                      \
            MFMA6(acc, A, Bf);                                                    \
        }                                                                         \
    }

// Per-iteration: barrier#1 (tile FT-1 reads done -> buf (FT+3)&3 reusable),
// stage tile FT+3, wait own tile-FT chunks (outstanding = future tiles only),
// barrier#2 (everyone's tile FT landed), compute.
#define ITER(FT, V3, V2)                                                          \
    {                                                                             \
        __builtin_amdgcn_s_barrier();                                             \
        __builtin_amdgcn_sched_barrier(0);                                        \
        if ((FT) + 3 < 8) STAGE((FT) + 3, ((FT) + 3) & 3);                        \
        if (w8) { asm volatile("s_waitcnt vmcnt(" #V3 ")" ::: "memory"); }        \
        else    { asm volatile("s_waitcnt vmcnt(" #V2 ")" ::: "memory"); }        \
        __builtin_amdgcn_sched_barrier(0);                                        \
        __builtin_amdgcn_s_barrier();                                             \
        __builtin_amdgcn_sched_barrier(0);                                        \
        COMPUTE(FT);                                                              \
    }

    // Prologue: stage tiles 0,1,2.
    STAGE(0, 0);
    STAGE(1, 1);
    STAGE(2, 2);

    ITER(0, 9, 6);
    ITER(1, 9, 6);
    ITER(2, 9, 6);
    ITER(3, 9, 6);
    ITER(4, 9, 6);
    ITER(5, 6, 4);
    ITER(6, 3, 2);
    ITER(7, 0, 0);

    __syncthreads();   // full drain before scratch overlays Pl[0]

    // argmax over m per b (numpy first-occurrence). Wave partial over its 32
    // cols; 16-lane butterfly; combine 8 mtg groups ascending (strict '>'
    // keeps lowest m on ties).
    float* pval = (float*)&Pl[0][0];          // [8][64]
    int*   pidx = (int*)&Pl[0][0] + 512;      // [8][64]
    int*   sidx = (int*)&Pl[0][0] + 1024;     // [64]
#pragma unroll
    for (int r = 0; r < 16; ++r) {
        float bv = acc[r];
        int   bi = rbm;
#pragma unroll
        for (int off = 16; off >= 1; off >>= 1) {
            const float ov = __shfl_xor(bv, off);
            const int   oi = __shfl_xor(bi, off);
            if (ov > bv || (ov == bv && oi < bi)) { bv = ov; bi = oi; }
        }
        if (r32 == 0) {
            const int b = bt * 32 + (r & 3) + 8 * (r >> 2) + 4 * kh;
            pval[mtg * 64 + b] = bv;
            pidx[mtg * 64 + b] = bi;
        }
    }
    __syncthreads();

    if (t < 64) {
        float bv = pval[t];
        int   bi = pidx[t];
#pragma unroll
        for (int g = 1; g < 8; ++g) {
            const float cv = pval[g * 64 + t];
            if (cv > bv) { bv = cv; bi = pidx[g * 64 + t]; }
        }
        sidx[t] = bi;
    }
    __syncthreads();

    // gather: out[b][l][:] = queue[l][sidx[b]][:]  (queue[l] is L2-hot)
    const int cb = t >> 6;     // 0..15
    const int cc = t & 63;     // float4 index within the 256-float row
#pragma unroll
    for (int b0 = 0; b0 < 64; b0 += 16) {
        const int b  = b0 + cb;
        const int mi = sidx[b];
        const float4 v = ld4(&queue[((size_t)l * M_ + mi) * F_ + cc * 4]);
        *reinterpret_cast<float4*>(&out[((size_t)b * L_ + l) * F_ + cc * 4]) = v;
    }
}

extern "C" void kernel_launch(void* const* d_in, const int* in_sizes, int n_in,
                              void* d_out, int out_size, void* d_ws, size_t ws_size,
                              hipStream_t stream) {
    const float* patch = (const float*)d_in[0];
    const float* queue = (const float*)d_in[1];
    float* out = (float*)d_out;
    mq_mfma_q4_kernel<<<dim3(L_), dim3(1024), 0, stream>>>(patch, queue, out);
}

// Round 15
// 143.672 us; speedup vs baseline: 1.0289x; 1.0289x over previous
//
#include <hip/hip_runtime.h>

#define B_ 64
#define L_ 1024
#define M_ 256
#define F_ 256

typedef __attribute__((ext_vector_type(8))) short short8;    // 8 bf16 (4 VGPR)
typedef __attribute__((ext_vector_type(16))) float f32x16;   // 32x32 MFMA C/D
typedef unsigned int u32;

struct Frag3 { short8 h, m, l; };

__device__ __forceinline__ u32 asu(float f) { union { float f; u32 u; } c; c.f = f; return c.u; }
__device__ __forceinline__ float asf(u32 u) { union { float f; u32 u; } c; c.u = u; return c.f; }
__device__ __forceinline__ u32 pack2(u32 lo, u32 hi) {
    return __builtin_amdgcn_perm(hi, lo, 0x07060302u);
}
__device__ __forceinline__ float4 ld4(const float* p) {
    return *reinterpret_cast<const float4*>(p);
}

// Exact 3-way bf16 truncation split of 8 fp32: x = h + m + l (top 24 mantissa bits).
__device__ __forceinline__ Frag3 split8(float4 a, float4 b) {
    float x[8] = {a.x, a.y, a.z, a.w, b.x, b.y, b.z, b.w};
    u32 xb[8], rb[8], sb[8];
#pragma unroll
    for (int e = 0; e < 8; ++e) {
        xb[e] = asu(x[e]);
        float hf = asf(xb[e] & 0xFFFF0000u);
        float r  = x[e] - hf;                 // exact
        rb[e] = asu(r);
        float mf = asf(rb[e] & 0xFFFF0000u);
        float r2 = r - mf;                    // exact
        sb[e] = asu(r2);
    }
    union { u32 w[4]; short8 s; } H, M, Lo;
#pragma unroll
    for (int d = 0; d < 4; ++d) {
        H.w[d]  = pack2(xb[2 * d], xb[2 * d + 1]);
        M.w[d]  = pack2(rb[2 * d], rb[2 * d + 1]);
        Lo.w[d] = pack2(sb[2 * d], sb[2 * d + 1]);
    }
    Frag3 f; f.h = H.s; f.m = M.s; f.l = Lo.s; return f;
}

#define MFMA6(ACC, A, Bf)                                                        \
    ACC = __builtin_amdgcn_mfma_f32_32x32x16_bf16((A).m, (Bf).m, ACC, 0, 0, 0);  \
    ACC = __builtin_amdgcn_mfma_f32_32x32x16_bf16((A).h, (Bf).l, ACC, 0, 0, 0);  \
    ACC = __builtin_amdgcn_mfma_f32_32x32x16_bf16((A).l, (Bf).h, ACC, 0, 0, 0);  \
    ACC = __builtin_amdgcn_mfma_f32_32x32x16_bf16((A).h, (Bf).m, ACC, 0, 0, 0);  \
    ACC = __builtin_amdgcn_mfma_f32_32x32x16_bf16((A).m, (Bf).h, ACC, 0, 0, 0);  \
    ACC = __builtin_amdgcn_mfma_f32_32x32x16_bf16((A).h, (Bf).h, ACC, 0, 0, 0)

// Loads for one k-step into a named 6-float4 buffer (ping-pong, static names).
#define LOADK(KK, A0, A1, B00, B01, B10, B11)                    \
    {                                                            \
        const float* ap_ = Abase + (KK) * 16;                    \
        const float* bp_ = Bbase + (KK) * 16;                    \
        A0  = ld4(ap_);                                          \
        A1  = ld4(ap_ + 4);                                      \
        B00 = ld4(bp_);                                          \
        B01 = ld4(bp_ + 4);                                      \
        B10 = ld4(bp_ + (size_t)32 * F_);                        \
        B11 = ld4(bp_ + (size_t)32 * F_ + 4);                    \
    }

#define BODY(A0, A1, B00, B01, B10, B11)                         \
    {                                                            \
        const Frag3 A  = split8(A0, A1);                         \
        const Frag3 Bf0 = split8(B00, B01);                      \
        MFMA6(acc0, A, Bf0);                                     \
        const Frag3 Bf1 = split8(B10, B11);                      \
        MFMA6(acc1, A, Bf1);                                     \
    }

#define FENCE() __builtin_amdgcn_sched_barrier(0)

// One block per l, 512 threads = 8 waves, NO LDS staging, NO main-loop
// barriers: every wave free-runs (perfect de-phasing, no convoy). Wave
// (bt=w&1, mtg=w>>1): b-rows bt*32..+31, m-cols mtg*64..+63. Register
// ping-pong prefetch, one k-step (16 f) ahead; sched_barrier(0) fences stop
// the compiler from sinking the prefetch back to its use (R9's failure:
// VGPR_Count 60 = pipeline torn down; fences force it to stay materialized).
// D layout: col(m)=lane&31, row=(reg&3)+8*(reg>>2)+4*(lane>>5)  [m74/m101].
__launch_bounds__(512, 2)
__global__ void mq_mfma32_kernel(const float* __restrict__ patch,
                                 const float* __restrict__ queue,
                                 float* __restrict__ out) {
    const int l    = blockIdx.x;
    const int t    = threadIdx.x;
    const int lane = t & 63;
    const int w    = t >> 6;        // 0..7
    const int bt   = w & 1;
    const int mtg  = w >> 1;        // 0..3
    const int r32  = lane & 31;
    const int kh   = lane >> 5;     // k-half: f-offset kh*8

    __shared__ float pval[4][64];
    __shared__ int   pidx[4][64];
    __shared__ int   sidx[64];

    f32x16 acc0 = (f32x16)0.f, acc1 = (f32x16)0.f;

    const float* Abase = patch + ((size_t)(bt * 32 + r32) * L_ + l) * F_ + kh * 8;
    const float* Bbase = queue + ((size_t)l * M_ + mtg * 64 + r32) * F_ + kh * 8;

    float4 xA0, xA1, xB00, xB01, xB10, xB11;   // buffer X
    float4 yA0, yA1, yB00, yB01, yB10, yB11;   // buffer Y

    LOADK(0, xA0, xA1, xB00, xB01, xB10, xB11);
    FENCE();

#pragma unroll 1
    for (int kk2 = 0; kk2 < 8; ++kk2) {
        // even step: prefetch odd step into Y, then compute from X
        LOADK(2 * kk2 + 1, yA0, yA1, yB00, yB01, yB10, yB11);
        FENCE();
        BODY(xA0, xA1, xB00, xB01, xB10, xB11);
        FENCE();
        // odd step: prefetch next even step into X, then compute from Y
        if (kk2 < 7) {
            LOADK(2 * kk2 + 2, xA0, xA1, xB00, xB01, xB10, xB11);
        }
        FENCE();
        BODY(yA0, yA1, yB00, yB01, yB10, yB11);
        FENCE();
    }

    // Per-wave argmax over its 64 m-cols for each of its 32 b-rows.
    // In-lane acc0->acc1 ascending m, strict '>' keeps lowest m; 32-lane
    // butterfly prefers lower idx on tie (numpy first-occurrence).
#pragma unroll
    for (int r = 0; r < 16; ++r) {
        float bv = acc0[r];
        int   bi = mtg * 64 + r32;
        {
            const float cv = acc1[r];
            const int   ci = mtg * 64 + 32 + r32;
            if (cv > bv) { bv = cv; bi = ci; }
        }
#pragma unroll
        for (int off = 16; off >= 1; off >>= 1) {
            const float ov = __shfl_xor(bv, off);
            const int   oi = __shfl_xor(bi, off);
            if (ov > bv || (ov == bv && oi < bi)) { bv = ov; bi = oi; }
        }
        if (r32 == 0) {
            const int b = bt * 32 + (r & 3) + 8 * (r >> 2) + 4 * kh;
            pval[mtg][b] = bv;
            pidx[mtg][b] = bi;
        }
    }
    __syncthreads();

    // Combine the four m-quarters; ascending mtg with strict '>' keeps the
    // lowest m on ties -> numpy first-occurrence.
    if (t < 64) {
        float bv = pval[0][t];
        int   bi = pidx[0][t];
#pragma unroll
        for (int g = 1; g < 4; ++g) {
            const float cv = pval[g][t];
            if (cv > bv) { bv = cv; bi = pidx[g][t]; }
        }
        sidx[t] = bi;
    }
    __syncthreads();

    // gather: out[b][l][:] = queue[l][sidx[b]][:]  (queue[l] is L2-hot)
    const int cb = t >> 6;     // 0..7
    const int cc = t & 63;     // float4 index within the 256-float row
#pragma unroll
    for (int b0 = 0; b0 < 64; b0 += 8) {
        const int b  = b0 + cb;
        const int mi = sidx[b];
        const float4 v = ld4(&queue[((size_t)l * M_ + mi) * F_ + cc * 4]);
        *reinterpret_cast<float4*>(&out[((size_t)b * L_ + l) * F_ + cc * 4]) = v;
    }
}

extern "C" void kernel_launch(void* const* d_in, const int* in_sizes, int n_in,
                              void* d_out, int out_size, void* d_ws, size_t ws_size,
                              hipStream_t stream) {
    const float* patch = (const float*)d_in[0];
    const float* queue = (const float*)d_in[1];
    float* out = (float*)d_out;
    mq_mfma32_kernel<<<dim3(L_), dim3(512), 0, stream>>>(patch, queue, out);
}

// Round 16
// 111.017 us; speedup vs baseline: 1.3316x; 1.2941x over previous
//
#include <hip/hip_runtime.h>

#define B_ 64
#define L_ 1024
#define M_ 256
#define F_ 256

typedef __attribute__((ext_vector_type(8))) short short8;    // 8 bf16 (4 VGPR)
typedef __attribute__((ext_vector_type(16))) float f32x16;   // 32x32 MFMA C/D
typedef unsigned int u32;

struct Frag3 { short8 h, m, l; };

__device__ __forceinline__ u32 asu(float f) { union { float f; u32 u; } c; c.f = f; return c.u; }
__device__ __forceinline__ float asf(u32 u) { union { float f; u32 u; } c; c.u = u; return c.f; }
__device__ __forceinline__ u32 pack2(u32 lo, u32 hi) {
    return __builtin_amdgcn_perm(hi, lo, 0x07060302u);
}
__device__ __forceinline__ float4 ld4(const float* p) {
    return *reinterpret_cast<const float4*>(p);
}
__device__ __forceinline__ short8 ld8s(const short* p) {
    return *reinterpret_cast<const short8*>(p);
}

// Exact 3-way bf16 truncation split of 8 fp32: x = h + m + l (top 24 mantissa bits).
__device__ __forceinline__ Frag3 split8(float4 a, float4 b) {
    float x[8] = {a.x, a.y, a.z, a.w, b.x, b.y, b.z, b.w};
    u32 xb[8], rb[8], sb[8];
#pragma unroll
    for (int e = 0; e < 8; ++e) {
        xb[e] = asu(x[e]);
        float hf = asf(xb[e] & 0xFFFF0000u);
        float r  = x[e] - hf;                 // exact
        rb[e] = asu(r);
        float mf = asf(rb[e] & 0xFFFF0000u);
        float r2 = r - mf;                    // exact
        sb[e] = asu(r2);
    }
    union { u32 w[4]; short8 s; } H, M, Lo;
#pragma unroll
    for (int d = 0; d < 4; ++d) {
        H.w[d]  = pack2(xb[2 * d], xb[2 * d + 1]);
        M.w[d]  = pack2(rb[2 * d], rb[2 * d + 1]);
        Lo.w[d] = pack2(sb[2 * d], sb[2 * d + 1]);
    }
    Frag3 f; f.h = H.s; f.m = M.s; f.l = Lo.s; return f;
}

#define MFMA6(ACC, A, Bf)                                                        \
    ACC = __builtin_amdgcn_mfma_f32_32x32x16_bf16((A).m, (Bf).m, ACC, 0, 0, 0);  \
    ACC = __builtin_amdgcn_mfma_f32_32x32x16_bf16((A).h, (Bf).l, ACC, 0, 0, 0);  \
    ACC = __builtin_amdgcn_mfma_f32_32x32x16_bf16((A).l, (Bf).h, ACC, 0, 0, 0);  \
    ACC = __builtin_amdgcn_mfma_f32_32x32x16_bf16((A).h, (Bf).m, ACC, 0, 0, 0);  \
    ACC = __builtin_amdgcn_mfma_f32_32x32x16_bf16((A).m, (Bf).h, ACC, 0, 0, 0);  \
    ACC = __builtin_amdgcn_mfma_f32_32x32x16_bf16((A).h, (Bf).h, ACC, 0, 0, 0)

// One block per l, 512 threads = 8 waves, 2 blocks/CU. SPLIT-ONCE: each tile
// (16 f) is loaded fp32->reg, truncation-split ONCE by its owner thread, and
// the h/m/l bf16 planes staged in LDS; every wave reads MFMA fragments
// directly as short8 (no consumer-side split -> block split work 384->160).
// Wave (bt=w&1, mtg=w>>1): b-rows bt*32..+31, m-cols mtg*64..+63.
// Single barrier per tile (dbuf; ft-1's barrier fences ft-2's reads).
// D layout: col(m)=lane&31, row=(reg&3)+8*(reg>>2)+4*(lane>>5)  [m74/m101].
__launch_bounds__(512, 2)
__global__ void mq_split1_kernel(const float* __restrict__ patch,
                                 const float* __restrict__ queue,
                                 float* __restrict__ out) {
    const int l    = blockIdx.x;
    const int t    = threadIdx.x;
    const int lane = t & 63;
    const int w    = t >> 6;        // 0..7
    const int bt   = w & 1;
    const int mtg  = w >> 1;        // 0..3
    const int r32  = lane & 31;
    const int kh   = lane >> 5;     // k-half: f-offset kh*8

    __shared__ __align__(16) short Qp[2][3][256 * 16];  // 48KB: h/m/l planes
    __shared__ __align__(16) short Pp[2][3][64 * 16];   // 12KB

    // ---- staging ownership: thread t owns Q row t>>1, half t&1 (8 f);
    //      threads 0..127 (waves 0,1) additionally own P row t>>1, half t&1.
    const int   srow = t >> 1;
    const int   shal = t & 1;
    const float* qsrc = queue + ((size_t)l * M_ + srow) * F_ + shal * 8;
    const float* psrc = patch + ((size_t)(srow & 63) * L_ + l) * F_ + shal * 8;
    const int   soff = srow * 16 + shal * 8;         // element offset in a Q plane
    const int   poff = (srow & 63) * 16 + shal * 8;  // element offset in a P plane
    const bool  doP = (t < 128);

    float4 qv0, qv1, pv0, pv1;

#define LOADG(FT)                                                   \
    {                                                               \
        qv0 = ld4(qsrc + (FT) * 16);                                \
        qv1 = ld4(qsrc + (FT) * 16 + 4);                            \
        if (doP) {                                                  \
            pv0 = ld4(psrc + (FT) * 16);                            \
            pv1 = ld4(psrc + (FT) * 16 + 4);                        \
        }                                                           \
    }

#define SPLITWRITE(BUF)                                             \
    {                                                               \
        const Frag3 q = split8(qv0, qv1);                           \
        *reinterpret_cast<short8*>(&Qp[BUF][0][soff]) = q.h;        \
        *reinterpret_cast<short8*>(&Qp[BUF][1][soff]) = q.m;        \
        *reinterpret_cast<short8*>(&Qp[BUF][2][soff]) = q.l;        \
        if (doP) {                                                  \
            const Frag3 p = split8(pv0, pv1);                       \
            *reinterpret_cast<short8*>(&Pp[BUF][0][poff]) = p.h;    \
            *reinterpret_cast<short8*>(&Pp[BUF][1][poff]) = p.m;    \
            *reinterpret_cast<short8*>(&Pp[BUF][2][poff]) = p.l;    \
        }                                                           \
    }

    f32x16 acc0 = (f32x16)0.f, acc1 = (f32x16)0.f;

    const int arow  = (bt * 32 + r32) * 16 + kh * 8;   // A frag offset in P plane
    const int brow0 = (mtg * 64 + r32) * 16 + kh * 8;  // B0 frag offset in Q plane
    const int brow1 = brow0 + 32 * 16;                 // B1 (+32 rows)

    LOADG(0);

#pragma unroll 1
    for (int ft = 0; ft < 16; ++ft) {
        const int buf = ft & 1;
        SPLITWRITE(buf);           // compiler auto-waits vmcnt for qv/pv use
        if (ft < 15) LOADG(ft + 1);   // issue next tile now; lands during compute
        __builtin_amdgcn_sched_barrier(0);   // pin loads before the barrier
        __syncthreads();           // lgkmcnt(0)+barrier: planes visible
        {
            Frag3 A, Bf;
            A.h = ld8s(&Pp[buf][0][arow]);
            A.m = ld8s(&Pp[buf][1][arow]);
            A.l = ld8s(&Pp[buf][2][arow]);
            Bf.h = ld8s(&Qp[buf][0][brow0]);
            Bf.m = ld8s(&Qp[buf][1][brow0]);
            Bf.l = ld8s(&Qp[buf][2][brow0]);
            MFMA6(acc0, A, Bf);
            Bf.h = ld8s(&Qp[buf][0][brow1]);
            Bf.m = ld8s(&Qp[buf][1][brow1]);
            Bf.l = ld8s(&Qp[buf][2][brow1]);
            MFMA6(acc1, A, Bf);
        }
        __builtin_amdgcn_sched_barrier(0);
    }

    __syncthreads();   // all compute done before scratch overlays Pp[0]

    // argmax over m per b (numpy first-occurrence; logic identical to R13).
    float* pval = (float*)&Pp[0][0][0];          // [4][64]
    int*   pidx = (int*)&Pp[0][0][0] + 256;      // [4][64]
    int*   sidx = (int*)&Pp[0][0][0] + 512;      // [64]
#pragma unroll
    for (int r = 0; r < 16; ++r) {
        float bv = acc0[r];
        int   bi = mtg * 64 + r32;
        {
            const float cv = acc1[r];
            const int   ci = mtg * 64 + 32 + r32;
            if (cv > bv) { bv = cv; bi = ci; }
        }
#pragma unroll
        for (int off = 16; off >= 1; off >>= 1) {
            const float ov = __shfl_xor(bv, off);
            const int   oi = __shfl_xor(bi, off);
            if (ov > bv || (ov == bv && oi < bi)) { bv = ov; bi = oi; }
        }
        if (r32 == 0) {
            const int b = bt * 32 + (r & 3) + 8 * (r >> 2) + 4 * kh;
            pval[mtg * 64 + b] = bv;
            pidx[mtg * 64 + b] = bi;
        }
    }
    __syncthreads();

    // Combine the four m-quarters; ascending mtg with strict '>' keeps the
    // lowest m on ties -> numpy first-occurrence.
    if (t < 64) {
        float bv = pval[t];
        int   bi = pidx[t];
#pragma unroll
        for (int g = 1; g < 4; ++g) {
            const float cv = pval[g * 64 + t];
            if (cv > bv) { bv = cv; bi = pidx[g * 64 + t]; }
        }
        sidx[t] = bi;
    }
    __syncthreads();

    // gather: out[b][l][:] = queue[l][sidx[b]][:]  (queue[l] is L2-hot)
    const int cb = t >> 6;     // 0..7
    const int cc = t & 63;     // float4 index within the 256-float row
#pragma unroll
    for (int b0 = 0; b0 < 64; b0 += 8) {
        const int b  = b0 + cb;
        const int mi = sidx[b];
        const float4 v = ld4(&queue[((size_t)l * M_ + mi) * F_ + cc * 4]);
        *reinterpret_cast<float4*>(&out[((size_t)b * L_ + l) * F_ + cc * 4]) = v;
    }
}

extern "C" void kernel_launch(void* const* d_in, const int* in_sizes, int n_in,
                              void* d_out, int out_size, void* d_ws, size_t ws_size,
                              hipStream_t stream) {
    const float* patch = (const float*)d_in[0];
    const float* queue = (const float*)d_in[1];
    float* out = (float*)d_out;
    mq_split1_kernel<<<dim3(L_), dim3(512), 0, stream>>>(patch, queue, out);
}

// Round 17
// 106.559 us; speedup vs baseline: 1.3873x; 1.0418x over previous
//
#include <hip/hip_runtime.h>

#define B_ 64
#define L_ 1024
#define M_ 256
#define F_ 256

typedef __attribute__((ext_vector_type(8))) short short8;    // 8 bf16 (4 VGPR)
typedef __attribute__((ext_vector_type(16))) float f32x16;   // 32x32 MFMA C/D
typedef unsigned int u32;

struct Frag3 { short8 h, m, l; };

__device__ __forceinline__ u32 asu(float f) { union { float f; u32 u; } c; c.f = f; return c.u; }
__device__ __forceinline__ float asf(u32 u) { union { float f; u32 u; } c; c.u = u; return c.f; }
__device__ __forceinline__ u32 pack2(u32 lo, u32 hi) {
    return __builtin_amdgcn_perm(hi, lo, 0x07060302u);
}
__device__ __forceinline__ float4 ld4(const float* p) {
    return *reinterpret_cast<const float4*>(p);
}

// Async 16B global->LDS DMA; LDS dest wave-uniform, per-lane source carries
// the XOR swizzle (m173 pattern, validated R6/R10).
__device__ __forceinline__ void async_cp16(const float* g, float* l) {
    __builtin_amdgcn_global_load_lds(
        (const __attribute__((address_space(1))) u32*)g,
        (__attribute__((address_space(3))) u32*)l,
        16, 0, 0);
}

// Exact 3-way bf16 truncation split of 8 fp32: x = h + m + l (top 24 mantissa bits).
__device__ __forceinline__ Frag3 split8(float4 a, float4 b) {
    float x[8] = {a.x, a.y, a.z, a.w, b.x, b.y, b.z, b.w};
    u32 xb[8], rb[8], sb[8];
#pragma unroll
    for (int e = 0; e < 8; ++e) {
        xb[e] = asu(x[e]);
        float hf = asf(xb[e] & 0xFFFF0000u);
        float r  = x[e] - hf;                 // exact
        rb[e] = asu(r);
        float mf = asf(rb[e] & 0xFFFF0000u);
        float r2 = r - mf;                    // exact
        sb[e] = asu(r2);
    }
    union { u32 w[4]; short8 s; } H, M, Lo;
#pragma unroll
    for (int d = 0; d < 4; ++d) {
        H.w[d]  = pack2(xb[2 * d], xb[2 * d + 1]);
        M.w[d]  = pack2(rb[2 * d], rb[2 * d + 1]);
        Lo.w[d] = pack2(sb[2 * d], sb[2 * d + 1]);
    }
    Frag3 f; f.h = H.s; f.m = M.s; f.l = Lo.s; return f;
}

#define MFMA6(ACC, A, Bf)                                                        \
    ACC = __builtin_amdgcn_mfma_f32_32x32x16_bf16((A).m, (Bf).m, ACC, 0, 0, 0);  \
    ACC = __builtin_amdgcn_mfma_f32_32x32x16_bf16((A).h, (Bf).l, ACC, 0, 0, 0);  \
    ACC = __builtin_amdgcn_mfma_f32_32x32x16_bf16((A).l, (Bf).h, ACC, 0, 0, 0);  \
    ACC = __builtin_amdgcn_mfma_f32_32x32x16_bf16((A).h, (Bf).m, ACC, 0, 0, 0);  \
    ACC = __builtin_amdgcn_mfma_f32_32x32x16_bf16((A).m, (Bf).h, ACC, 0, 0, 0);  \
    ACC = __builtin_amdgcn_mfma_f32_32x32x16_bf16((A).h, (Bf).h, ACC, 0, 0, 0)

// R13 + T5 s_setprio: identical schedule (8 waves, LDS dbuf, DMA staging,
// raw s_barrier pairs + counted vmcnt(5)) with the compute phase wrapped in
// setprio(1)/setprio(0). Two independently-phased blocks/CU: setprio makes
// the CU scheduler prefer compute-phase waves over the other block's
// staging/waiting waves (T5 mechanism, m218b).
// D layout: col(m)=lane&31, row=(reg&3)+8*(reg>>2)+4*(lane>>5)  [m74/m101].
__launch_bounds__(512, 2)
__global__ void mq_mfma_lds_kernel(const float* __restrict__ patch,
                                   const float* __restrict__ queue,
                                   float* __restrict__ out) {
    const int l    = blockIdx.x;
    const int t    = threadIdx.x;
    const int lane = t & 63;
    const int w    = t >> 6;        // 0..7
    const int bt   = w & 1;
    const int mtg  = w >> 1;        // 0..3
    const int r32  = lane & 31;
    const int kh   = lane >> 5;     // k-half: f-offset kh*8

    __shared__ __align__(16) float Ql[2][256 * 32];  // 2 x 32KB
    __shared__ __align__(16) float Pl[2][64 * 32];   // 2 x 8KB   (total 80KB)

    // ---- staging geometry: wave w stages Q rows w*32..w*32+31 (4 chunks)
    //      and P rows w*8..w*8+7 (1 chunk); swizzled source chunk lcol^lrow.
    const int lrow = lane >> 3;     // 0..7: row within an 8-row chunk
    const int lcol = lane & 7;      // 0..7: 16B slot within a 128B row
    const float* qsrcw = queue + ((size_t)l * M_ + w * 32 + lrow) * F_ + (lcol ^ lrow) * 4;
    const float* psrcw = patch + ((size_t)(w * 8 + lrow) * L_ + l) * F_ + (lcol ^ lrow) * 4;

#define STAGE(FT, BUF)                                                            \
    {                                                                             \
        _Pragma("unroll")                                                         \
        for (int k = 0; k < 4; ++k)                                               \
            async_cp16(qsrcw + (size_t)k * 8 * F_ + (FT) * 32,                    \
                       &Ql[BUF][(w * 4 + k) * 256]);                              \
        async_cp16(psrcw + (FT) * 32, &Pl[BUF][w * 256]);                         \
    }

    f32x16 acc0 = (f32x16)0.f, acc1 = (f32x16)0.f;

    STAGE(0, 0);

    const int s7 = r32 & 7;          // read-side XOR (row&7 == r32&7 everywhere)
    const int ra = bt * 32 + r32;    // P row for this lane
    const int rb0 = mtg * 64 + r32;  // first Q row
    const int rb1 = mtg * 64 + 32 + r32;

#pragma unroll 1
    for (int ft = 0; ft < 8; ++ft) {
        // barrier#1: all waves finished reading buf[(ft+1)&1] (tile ft-1).
        __builtin_amdgcn_s_barrier();
        __builtin_amdgcn_sched_barrier(0);
        if (ft < 7) {
            STAGE(ft + 1, (ft + 1) & 1);
            // own tile-ft chunks (oldest 5 of 10 outstanding) retired;
            // tile ft+1's 5 stay in flight across the whole compute phase.
            asm volatile("s_waitcnt vmcnt(5)" ::: "memory");
        } else {
            asm volatile("s_waitcnt vmcnt(0)" ::: "memory");
        }
        __builtin_amdgcn_sched_barrier(0);
        // barrier#2: every wave's tile-ft chunks have landed.
        __builtin_amdgcn_s_barrier();
        __builtin_amdgcn_sched_barrier(0);

        __builtin_amdgcn_s_setprio(1);   // T5: favor compute-phase waves
        const float* Qb = Ql[ft & 1];
        const float* Pb = Pl[ft & 1];
#pragma unroll
        for (int kk = 0; kk < 2; ++kk) {
            const int c0 = kk * 4 + kh * 2;   // first 16B chunk of this fragment
            const float4 a0 = ld4(&Pb[ra * 32 + ((c0 ^ s7) * 4)]);
            const float4 a1 = ld4(&Pb[ra * 32 + (((c0 + 1) ^ s7) * 4)]);
            const Frag3 A = split8(a0, a1);
            {
                const float4 b0 = ld4(&Qb[rb0 * 32 + ((c0 ^ s7) * 4)]);
                const float4 b1 = ld4(&Qb[rb0 * 32 + (((c0 + 1) ^ s7) * 4)]);
                const Frag3 Bf = split8(b0, b1);
                MFMA6(acc0, A, Bf);
            }
            {
                const float4 b0 = ld4(&Qb[rb1 * 32 + ((c0 ^ s7) * 4)]);
                const float4 b1 = ld4(&Qb[rb1 * 32 + (((c0 + 1) ^ s7) * 4)]);
                const Frag3 Bf = split8(b0, b1);
                MFMA6(acc1, A, Bf);
            }
        }
        __builtin_amdgcn_s_setprio(0);
        __builtin_amdgcn_sched_barrier(0);
    }

    __syncthreads();   // full drain before scratch overlays Pl[0]

    // argmax over m per b (numpy first-occurrence). Wave partials over its
    // 64 cols; in-lane acc0->acc1 ascending m, strict '>' keeps lowest m.
    float* pval = (float*)&Pl[0][0];          // [4][64]
    int*   pidx = (int*)&Pl[0][0] + 256;      // [4][64]
    int*   sidx = (int*)&Pl[0][0] + 512;      // [64]
#pragma unroll
    for (int r = 0; r < 16; ++r) {
        float bv = acc0[r];
        int   bi = mtg * 64 + r32;
        {
            const float cv = acc1[r];
            const int   ci = mtg * 64 + 32 + r32;
            if (cv > bv) { bv = cv; bi = ci; }
        }
#pragma unroll
        for (int off = 16; off >= 1; off >>= 1) {
            const float ov = __shfl_xor(bv, off);
            const int   oi = __shfl_xor(bi, off);
            if (ov > bv || (ov == bv && oi < bi)) { bv = ov; bi = oi; }
        }
        if (r32 == 0) {
            const int b = bt * 32 + (r & 3) + 8 * (r >> 2) + 4 * kh;
            pval[mtg * 64 + b] = bv;
            pidx[mtg * 64 + b] = bi;
        }
    }
    __syncthreads();

    // Combine the four m-quarters; ascending mtg with strict '>' keeps the
    // lowest m on ties -> numpy first-occurrence.
    if (t < 64) {
        float bv = pval[t];
        int   bi = pidx[t];
#pragma unroll
        for (int g = 1; g < 4; ++g) {
            const float cv = pval[g * 64 + t];
            if (cv > bv) { bv = cv; bi = pidx[g * 64 + t]; }
        }
        sidx[t] = bi;
    }
    __syncthreads();

    // gather: out[b][l][:] = queue[l][sidx[b]][:]  (queue[l] is L2-hot)
    const int cb = t >> 6;     // 0..7
    const int cc = t & 63;     // float4 index within the 256-float row
#pragma unroll
    for (int b0 = 0; b0 < 64; b0 += 8) {
        const int b  = b0 + cb;
        const int mi = sidx[b];
        const float4 v = ld4(&queue[((size_t)l * M_ + mi) * F_ + cc * 4]);
        *reinterpret_cast<float4*>(&out[((size_t)b * L_ + l) * F_ + cc * 4]) = v;
    }
}

extern "C" void kernel_launch(void* const* d_in, const int* in_sizes, int n_in,
                              void* d_out, int out_size, void* d_ws, size_t ws_size,
                              hipStream_t stream) {
    const float* patch = (const float*)d_in[0];
    const float* queue = (const float*)d_in[1];
    float* out = (float*)d_out;
    mq_mfma_lds_kernel<<<dim3(L_), dim3(512), 0, stream>>>(patch, queue, out);
}

// Round 18
// 101.139 us; speedup vs baseline: 1.4617x; 1.0536x over previous
//
#include <hip/hip_runtime.h>

#define B_ 64
#define L_ 1024
#define M_ 256
#define F_ 256
#define LSTEP 512   // grid = 512; block handles l = bid and bid+512

typedef __attribute__((ext_vector_type(8))) short short8;    // 8 bf16 (4 VGPR)
typedef __attribute__((ext_vector_type(16))) float f32x16;   // 32x32 MFMA C/D
typedef unsigned int u32;

struct Frag3 { short8 h, m, l; };

__device__ __forceinline__ u32 asu(float f) { union { float f; u32 u; } c; c.f = f; return c.u; }
__device__ __forceinline__ float asf(u32 u) { union { float f; u32 u; } c; c.u = u; return c.f; }
__device__ __forceinline__ u32 pack2(u32 lo, u32 hi) {
    return __builtin_amdgcn_perm(hi, lo, 0x07060302u);
}
__device__ __forceinline__ float4 ld4(const float* p) {
    return *reinterpret_cast<const float4*>(p);
}

// Async 16B global->LDS DMA; LDS dest wave-uniform, per-lane source carries
// the XOR swizzle (m173 pattern, validated R6/R10).
__device__ __forceinline__ void async_cp16(const float* g, float* l) {
    __builtin_amdgcn_global_load_lds(
        (const __attribute__((address_space(1))) u32*)g,
        (__attribute__((address_space(3))) u32*)l,
        16, 0, 0);
}

// Exact 3-way bf16 truncation split of 8 fp32: x = h + m + l (top 24 mantissa bits).
__device__ __forceinline__ Frag3 split8(float4 a, float4 b) {
    float x[8] = {a.x, a.y, a.z, a.w, b.x, b.y, b.z, b.w};
    u32 xb[8], rb[8], sb[8];
#pragma unroll
    for (int e = 0; e < 8; ++e) {
        xb[e] = asu(x[e]);
        float hf = asf(xb[e] & 0xFFFF0000u);
        float r  = x[e] - hf;                 // exact
        rb[e] = asu(r);
        float mf = asf(rb[e] & 0xFFFF0000u);
        float r2 = r - mf;                    // exact
        sb[e] = asu(r2);
    }
    union { u32 w[4]; short8 s; } H, M, Lo;
#pragma unroll
    for (int d = 0; d < 4; ++d) {
        H.w[d]  = pack2(xb[2 * d], xb[2 * d + 1]);
        M.w[d]  = pack2(rb[2 * d], rb[2 * d + 1]);
        Lo.w[d] = pack2(sb[2 * d], sb[2 * d + 1]);
    }
    Frag3 f; f.h = H.s; f.m = M.s; f.l = Lo.s; return f;
}

#define MFMA6(ACC, A, Bf)                                                        \
    ACC = __builtin_amdgcn_mfma_f32_32x32x16_bf16((A).m, (Bf).m, ACC, 0, 0, 0);  \
    ACC = __builtin_amdgcn_mfma_f32_32x32x16_bf16((A).h, (Bf).l, ACC, 0, 0, 0);  \
    ACC = __builtin_amdgcn_mfma_f32_32x32x16_bf16((A).l, (Bf).h, ACC, 0, 0, 0);  \
    ACC = __builtin_amdgcn_mfma_f32_32x32x16_bf16((A).h, (Bf).m, ACC, 0, 0, 0);  \
    ACC = __builtin_amdgcn_mfma_f32_32x32x16_bf16((A).m, (Bf).h, ACC, 0, 0, 0);  \
    ACC = __builtin_amdgcn_mfma_f32_32x32x16_bf16((A).h, (Bf).h, ACC, 0, 0, 0)

// R13 core fused across two l's per block (grid 512, all blocks resident).
// 512 threads = 8 waves, LDS dbuf 80KB -> 2 blocks/CU. Cross-boundary
// software pipeline: at (li=0, ft=7) — where R13 staged nothing — we stage
// l2's tile 0, which lands during l1's whole epilogue; the DMA stream never
// drains at the l-boundary. Epilogue scratch lives in buf1 (cross-staged
// tile 0 targets buf0 — no conflict).
// D layout: col(m)=lane&31, row=(reg&3)+8*(reg>>2)+4*(lane>>5)  [m74/m101].
__launch_bounds__(512, 2)
__global__ void mq_mfma_2l_kernel(const float* __restrict__ patch,
                                  const float* __restrict__ queue,
                                  float* __restrict__ out) {
    const int l0   = blockIdx.x;
    const int t    = threadIdx.x;
    const int lane = t & 63;
    const int w    = t >> 6;        // 0..7
    const int bt   = w & 1;
    const int mtg  = w >> 1;        // 0..3
    const int r32  = lane & 31;
    const int kh   = lane >> 5;     // k-half: f-offset kh*8

    __shared__ __align__(16) float Ql[2][256 * 32];  // 2 x 32KB
    __shared__ __align__(16) float Pl[2][64 * 32];   // 2 x 8KB   (total 80KB)

    // ---- staging geometry (R13): wave w stages Q rows w*32..+31 (4 chunks)
    //      and P rows w*8..+7 (1 chunk); swizzled source chunk lcol^lrow.
    const int lrow = lane >> 3;
    const int lcol = lane & 7;
    const float* qsrcw = queue + ((size_t)l0 * M_ + w * 32 + lrow) * F_ + (lcol ^ lrow) * 4;
    const float* psrcw = patch + ((size_t)(w * 8 + lrow) * L_ + l0) * F_ + (lcol ^ lrow) * 4;
    const size_t QD = (size_t)LSTEP * M_ * F_;   // Q offset l -> l+512
    const size_t PD = (size_t)LSTEP * F_;        // P offset l -> l+512

#define STAGE(QOFF, POFF, BUF)                                                    \
    {                                                                             \
        _Pragma("unroll")                                                         \
        for (int k = 0; k < 4; ++k)                                               \
            async_cp16(qsrcw + (size_t)k * 8 * F_ + (QOFF),                       \
                       &Ql[BUF][(w * 4 + k) * 256]);                              \
        async_cp16(psrcw + (POFF), &Pl[BUF][w * 256]);                            \
    }

    f32x16 acc0 = (f32x16)0.f, acc1 = (f32x16)0.f;

    STAGE(0, 0, 0);

    const int s7  = r32 & 7;         // read-side XOR (row&7 == r32&7 everywhere)
    const int ra  = bt * 32 + r32;   // P row for this lane
    const int rb0 = mtg * 64 + r32;  // first Q row
    const int rb1 = mtg * 64 + 32 + r32;

    // epilogue scratch in buf1 (never targeted by a cross-boundary stage)
    float* pval = (float*)&Pl[1][0];          // [4][64]
    int*   pidx = (int*)&Pl[1][0] + 256;      // [4][64]
    int*   sidx = (int*)&Pl[1][0] + 512;      // [64]

#pragma unroll
    for (int li = 0; li < 2; ++li) {
        const size_t qo = (size_t)li * QD;
        const size_t po = (size_t)li * PD;

#pragma unroll 1
        for (int ft = 0; ft < 8; ++ft) {
            // barrier#1: all waves done reading buf[(ft+1)&1] / epilogue scratch.
            __builtin_amdgcn_s_barrier();
            __builtin_amdgcn_sched_barrier(0);
            if (ft < 7) {
                STAGE(qo + (ft + 1) * 32, po + (ft + 1) * 32, (ft + 1) & 1);
                asm volatile("s_waitcnt vmcnt(5)" ::: "memory");
            } else if (li == 0) {
                // cross-boundary: stage l2's tile 0 into buf0 -> lands during
                // l1's epilogue; stream never drains.
                STAGE(QD, PD, 0);
                asm volatile("s_waitcnt vmcnt(5)" ::: "memory");
            } else {
                asm volatile("s_waitcnt vmcnt(0)" ::: "memory");
            }
            __builtin_amdgcn_sched_barrier(0);
            // barrier#2: every wave's current-tile chunks have landed.
            __builtin_amdgcn_s_barrier();
            __builtin_amdgcn_sched_barrier(0);

            const float* Qb = Ql[ft & 1];
            const float* Pb = Pl[ft & 1];
#pragma unroll
            for (int kk = 0; kk < 2; ++kk) {
                const int c0 = kk * 4 + kh * 2;
                const float4 a0 = ld4(&Pb[ra * 32 + ((c0 ^ s7) * 4)]);
                const float4 a1 = ld4(&Pb[ra * 32 + (((c0 + 1) ^ s7) * 4)]);
                const Frag3 A = split8(a0, a1);
                {
                    const float4 b0 = ld4(&Qb[rb0 * 32 + ((c0 ^ s7) * 4)]);
                    const float4 b1 = ld4(&Qb[rb0 * 32 + (((c0 + 1) ^ s7) * 4)]);
                    const Frag3 Bf = split8(b0, b1);
                    MFMA6(acc0, A, Bf);
                }
                {
                    const float4 b0 = ld4(&Qb[rb1 * 32 + ((c0 ^ s7) * 4)]);
                    const float4 b1 = ld4(&Qb[rb1 * 32 + (((c0 + 1) ^ s7) * 4)]);
                    const Frag3 Bf = split8(b0, b1);
                    MFMA6(acc1, A, Bf);
                }
            }
        }

        // ---- epilogue for l = l0 + li*LSTEP (scratch = buf1; ft7 compute
        //      read buf1, so one barrier makes it reusable; l2's tile-0 DMA
        //      is concurrently landing in buf0).
        __builtin_amdgcn_s_barrier();

        // argmax over m per b (numpy first-occurrence, logic as R13).
#pragma unroll
        for (int r = 0; r < 16; ++r) {
            float bv = acc0[r];
            int   bi = mtg * 64 + r32;
            {
                const float cv = acc1[r];
                const int   ci = mtg * 64 + 32 + r32;
                if (cv > bv) { bv = cv; bi = ci; }
            }
#pragma unroll
            for (int off = 16; off >= 1; off >>= 1) {
                const float ov = __shfl_xor(bv, off);
                const int   oi = __shfl_xor(bi, off);
                if (ov > bv || (ov == bv && oi < bi)) { bv = ov; bi = oi; }
            }
            if (r32 == 0) {
                const int b = bt * 32 + (r & 3) + 8 * (r >> 2) + 4 * kh;
                pval[mtg * 64 + b] = bv;
                pidx[mtg * 64 + b] = bi;
            }
        }
        __syncthreads();

        if (t < 64) {
            float bv = pval[t];
            int   bi = pidx[t];
#pragma unroll
            for (int g = 1; g < 4; ++g) {
                const float cv = pval[g * 64 + t];
                if (cv > bv) { bv = cv; bi = pidx[g * 64 + t]; }
            }
            sidx[t] = bi;
        }
        __syncthreads();

        // gather: out[b][l][:] = queue[l][sidx[b]][:]  (queue[l] is L2-hot)
        {
            const int lcur = l0 + li * LSTEP;
            const int cb = t >> 6;     // 0..7
            const int cc = t & 63;
#pragma unroll
            for (int b0 = 0; b0 < 64; b0 += 8) {
                const int b  = b0 + cb;
                const int mi = sidx[b];
                const float4 v = ld4(&queue[((size_t)lcur * M_ + mi) * F_ + cc * 4]);
                *reinterpret_cast<float4*>(&out[((size_t)b * L_ + lcur) * F_ + cc * 4]) = v;
            }
        }

        // reset accumulators for the second l
        acc0 = (f32x16)0.f;
        acc1 = (f32x16)0.f;
    }
}

extern "C" void kernel_launch(void* const* d_in, const int* in_sizes, int n_in,
                              void* d_out, int out_size, void* d_ws, size_t ws_size,
                              hipStream_t stream) {
    const float* patch = (const float*)d_in[0];
    const float* queue = (const float*)d_in[1];
    float* out = (float*)d_out;
    mq_mfma_2l_kernel<<<dim3(LSTEP), dim3(512), 0, stream>>>(patch, queue, out);
}